// Round 16
// baseline (4880.601 us; speedup 1.0000x reference)
//
#include <hip/hip_runtime.h>
#include <math.h>

// ---------------- problem constants ----------------
constexpr int B_ = 4, C_ = 16, O_ = 8, H_ = 192, W_ = 192;
constexpr int KS_ = 7, NL_ = 4, KJ = 125;          // KJ = MS^3
constexpr int HW_  = H_ * W_;                      // 36864
constexpr int OHW_ = O_ * HW_;                     // 294912
constexpr int COHW_ = C_ * OHW_;                   // 4718592
constexpr int NTOT = B_ * COHW_;                   // 18874368 elements
constexpr float EPS_ = 1e-5f;
constexpr float BIGF = 1e30f;
constexpr int NPLANES = B_ * C_ * O_;              // 512
constexpr float INVN_ = 1.0f / (float)(B_ * O_ * HW_);

// morph tile geometry: 64x16 output block, 256 threads = 4 waves x 4 rows/thread.
// DS instr per output drops 1.5 -> 1.25 (the measured bottleneck is the DS pipe's
// ~5.8 cyc/instr rate: R14's 528 us == 99% of that ceiling at 1.5/output).
// Tile 5 x 22 x 70 = 30.8 KB -> 5 blocks/CU x 4 waves = 20 waves/CU.
constexpr int CW_T = 64;               // output cols per block
constexpr int CR_T = 16;               // output rows per block
constexpr int TW_T = CW_T + 6;         // 70: tile row stride
constexpr int TR_T = CR_T + 6;         // 22: tile rows
constexpr int TP_T = TW_T * TR_T;      // 1540: tile plane

typedef float af2 __attribute__((ext_vector_type(2), aligned(4)));  // ds_read2_b32

// static per-(o,j) morph geometry record (32 B, layer-independent) — lives in the dead
// lift-weight region of the workspace, so total footprint == the proven R9 layout.
struct alignas(32) Geo6 {
    int   off;                         // (dt+2)*TP + (dy0+3)*TW + (dx0+3)
    float w00, w01, w10, w11;
    int   pad0, pad1, pad2;
};

// ---------------- lift: rotated weights (double math == numpy) ----------------
__global__ void k_lift_weights(const float* __restrict__ w, float* __restrict__ wr) {
    int idx = blockIdx.x * blockDim.x + threadIdx.x;
    if (idx >= C_ * O_ * 3 * 49) return;
    int q = idx % 49;
    int i = (idx / 49) % 3;
    int o = (idx / (49 * 3)) % O_;
    int c = idx / (49 * 3 * O_);
    const double ctr = (KS_ - 1) / 2.0;
    int qy = q / KS_, qx = q % KS_;
    double ys = qy - ctr, xs = qx - ctr;
    double th = 2.0 * M_PI * (double)o / (double)O_;
    double sy = cos(th) * ys + sin(th) * xs + ctr;
    double sx = -sin(th) * ys + cos(th) * xs + ctr;
    double y0 = floor(sy), x0 = floor(sx);
    double fy = sy - y0, fx = sx - x0;
    double acc = 0.0;
    for (int dy = 0; dy < 2; dy++)
        for (int dx = 0; dx < 2; dx++) {
            int yi = (int)y0 + dy, xi = (int)x0 + dx;
            if (yi >= 0 && yi < KS_ && xi >= 0 && xi < KS_) {
                double wt = (dy ? fy : 1.0 - fy) * (dx ? fx : 1.0 - fx);
                acc += wt * (double)w[(c * 3 + i) * 49 + yi * KS_ + xi];
            }
        }
    wr[idx] = (float)acc;   // layout [c][o][i][q]
}

// ---------------- lift conv, reflect padding handled by index math ----------------
__global__ __launch_bounds__(192) void k_lift_conv(const float* __restrict__ x,
                                                   const float* __restrict__ wr,
                                                   float* __restrict__ u) {
    __shared__ float wsm[3 * 49];
    int h = blockIdx.x;
    int bco = blockIdx.y;               // b*C*O + c*O + o
    int o = bco % O_;
    int c = (bco / O_) % C_;
    int b = bco / (O_ * C_);
    const float* wp = wr + (size_t)(c * O_ + o) * 3 * 49;
    for (int t = threadIdx.x; t < 147; t += blockDim.x) wsm[t] = wp[t];
    __syncthreads();
    int wI = threadIdx.x;
    float acc = 0.f;
    for (int i = 0; i < 3; i++) {
        const float* xp = x + (size_t)(b * 3 + i) * HW_;
        for (int kh = 0; kh < 7; kh++) {
            int hy = h + kh - 3;
            hy = hy < 0 ? -hy : (hy >= H_ ? 2 * H_ - 2 - hy : hy);
            const float* xrow = xp + hy * W_;
            for (int kw = 0; kw < 7; kw++) {
                int wx = wI + kw - 3;
                wx = wx < 0 ? -wx : (wx >= W_ ? 2 * W_ - 2 - wx : wx);
                acc += wsm[i * 49 + kh * 7 + kw] * xrow[wx];
            }
        }
    }
    u[(size_t)bco * HW_ + h * W_ + wI] = acc;
}

// ---------------- batchnorm stats over (B,O,H,W) per channel (apply fused into readers) ------
__global__ __launch_bounds__(256) void k_bn_reduce(const float* __restrict__ u,
                                                   float* __restrict__ sums) {
    int c = (blockIdx.x / O_) % C_;
    const float* p = u + (size_t)blockIdx.x * HW_;
    float s = 0.f, s2 = 0.f;
    for (int t = threadIdx.x; t < HW_; t += blockDim.x) {
        float v = p[t];
        s += v; s2 += v * v;
    }
    for (int off = 32; off; off >>= 1) {
        s  += __shfl_down(s, off, 64);
        s2 += __shfl_down(s2, off, 64);
    }
    __shared__ float sh[8];
    int lane = threadIdx.x & 63, wid = threadIdx.x >> 6;
    if (lane == 0) { sh[wid] = s; sh[4 + wid] = s2; }
    __syncthreads();
    if (threadIdx.x == 0) {
        s = sh[0] + sh[1] + sh[2] + sh[3];
        s2 = sh[4] + sh[5] + sh[6] + sh[7];
        atomicAdd(&sums[c], s);
        atomicAdd(&sums[C_ + c], s2);
    }
}

// ---------------- convect: 8-tap trilinear gather, BN fused on read, 2 rows/thread ------------
__global__ __launch_bounds__(192) void k_convect(const float* __restrict__ u,
                                                 const float* __restrict__ g,
                                                 const float* __restrict__ sums,
                                                 const float* __restrict__ gamma,
                                                 const float* __restrict__ beta,
                                                 float* __restrict__ out) {
    int h0 = blockIdx.x * 2;
    int bco = blockIdx.y;
    int o = bco % O_;
    int c = (bco / O_) % C_;
    int b = bco / (O_ * C_);
    float m = sums[c] * INVN_;
    float var = sums[C_ + c] * INVN_ - m * m;
    float alpha = rsqrtf(var + EPS_) * gamma[c];
    float bshift = beta[c] - m * alpha;
    float gx = g[c * 3 + 0], gy = g[c * 3 + 1], gth = g[c * 3 + 2];
    float th = ((float)(2.0 * M_PI) * (float)o) / (float)O_;
    float ct = cosf(th), st = sinf(th);
    float sx = ct * gx - st * gy;
    float sy = st * gx + ct * gy;
    float so = gth / (float)(2.0 * M_PI / (double)O_);
    float o_src = (float)o - so;
    float o0f = floorf(o_src); float fo = o_src - o0f;
    int o0 = (int)o0f;
    float ny = -sy; float y0f = floorf(ny); float fy = ny - y0f; int y0 = (int)y0f;
    float nx = -sx; float x0f = floorf(nx); float fx = nx - x0f; int x0 = (int)x0f;
    int oiA = ((o0 % O_) + O_) % O_;
    int oiB = (oiA + 1) % O_;
    const float* base = u + (size_t)(b * C_ + c) * OHW_;
    int wI = threadIdx.x;
#pragma unroll
    for (int r = 0; r < 2; r++) {
        int h = h0 + r;
        float acc = 0.f;
        for (int dd = 0; dd < 2; dd++) {
            float wo = dd ? fo : 1.0f - fo;
            const float* up = base + (size_t)(dd ? oiB : oiA) * HW_;
            for (int dy = 0; dy < 2; dy++) {
                int yy = h + y0 + dy;
                yy = min(max(yy, 0), H_ - 1);
                float wy = dy ? fy : 1.0f - fy;
                const float* row = up + yy * W_;
                for (int dx = 0; dx < 2; dx++) {
                    int xx = wI + x0 + dx;
                    xx = min(max(xx, 0), W_ - 1);
                    float wgt = wo * wy * (dx ? fx : 1.0f - fx);
                    acc += wgt * row[xx];
                }
            }
        }
        out[(size_t)bco * HW_ + h * W_ + wI] = fmaf(alpha, acc, bshift);
    }
}

// ---------------- morph static geometry (double math == numpy) ----------------
__global__ void k_morph_geo(int* __restrict__ dy0t, int* __restrict__ dx0t,
                            float* __restrict__ fyt, float* __restrict__ fxt,
                            int* __restrict__ dot_, float* __restrict__ c123) {
    int idx = blockIdx.x * blockDim.x + threadIdx.x;
    if (idx >= KJ * O_) return;
    int j = idx / O_, o = idx % O_;
    int dt = j / 25 - 2;
    int dy = (j / 5) % 5 - 2;
    int dx = j % 5 - 2;
    double dth = 2.0 * M_PI / (double)O_;
    double th = (double)o * dth;
    double gx = cos(th) * (double)dx - sin(th) * (double)dy;
    double gy = sin(th) * (double)dx + cos(th) * (double)dy;
    dx0t[j * O_ + o] = (int)floor(gx);
    fxt[j * O_ + o] = (float)(gx - floor(gx));
    dy0t[j * O_ + o] = (int)floor(gy);
    fyt[j * O_ + o] = (float)(gy - floor(gy));
    if (o == 0) {
        dot_[j] = dt;
        double a = (double)dt * dth;
        c123[j * 3 + 0] = (float)(cos(a / 2) * dx + sin(a / 2) * dy);
        c123[j * 3 + 1] = (float)(-sin(a / 2) * dx + cos(a / 2) * dy);
        c123[j * 3 + 2] = (float)a;
    }
}

__global__ void k_morph_kern(const float* __restrict__ wm, const float* __restrict__ c123,
                             float* __restrict__ kern, float nu_f, float eh_f) {
    int idx = blockIdx.x * blockDim.x + threadIdx.x;
    if (idx >= C_ * KJ) return;
    int c = idx / KJ, j = idx % KJ;
    float C1 = c123[j * 3 + 0], C2 = c123[j * 3 + 1], C3 = c123[j * 3 + 2];
    float rho2 = wm[c * 3 + 0] * C1 * C1 + wm[c * 3 + 1] * C2 * C2 + wm[c * 3 + 2] * C3 * C3;
    kern[c * KJ + j] = nu_f * powf(rho2, eh_f);
}

// ---------------- pack static per-(o,j) geometry (once per launch, into dead wr region) ------
__global__ void k_geo_pack6(const int* __restrict__ dy0t, const int* __restrict__ dx0t,
                            const float* __restrict__ fyt, const float* __restrict__ fxt,
                            const int* __restrict__ dot_, Geo6* __restrict__ geo) {
    int idx = blockIdx.x * blockDim.x + threadIdx.x;
    if (idx >= O_ * KJ) return;
    int j = idx % KJ;
    int o = idx / KJ;
    float fy = fyt[j * O_ + o];
    float fx = fxt[j * O_ + o];
    float wy0 = 1.0f - fy, wx0 = 1.0f - fx;
    Geo6 g;
    g.off = (dot_[j] + 2) * TP_T + (dy0t[j * O_ + o] + 3) * TW_T + (dx0t[j * O_ + o] + 3);
    g.w00 = wy0 * wx0;
    g.w01 = wy0 * fx;
    g.w10 = fy * wx0;
    g.w11 = fy * fx;
    g.pad0 = 0; g.pad1 = 0; g.pad2 = 0;
    geo[o * KJ + j] = g;
}

// ---------------- morph main: 64x16 tile, 256 threads, 4 rows/thread, 20 waves/CU ------------
// Per-output math / j order / fma chain identical to R14 (RPT=4 pair structure == R11's,
// proven); DS instructions per output drop 1.5 -> 1.25 — the measured bottleneck.
template <int DIL>
__global__ __launch_bounds__(256) void k_morph(const float* __restrict__ u,
                                               const Geo6* __restrict__ geo,
                                               const float* __restrict__ kern,
                                               float* __restrict__ out) {
    constexpr int CW = CW_T, CR = CR_T, TW = TW_T, TP = TP_T;
    constexpr int RPT = 4;             // rows per thread
    int cx = blockIdx.x % 3;           // col strip (W/64 = 3)
    int hs = blockIdx.x / 3;           // row strip (H/16 = 12)
    int h0 = hs * CR;
    int w0 = cx * CW;
    int bco = blockIdx.y;
    int o = bco % O_;
    int c = (bco / O_) % C_;
    int b = bco / (O_ * C_);

    __shared__ float tile[5 * TP];     // 30800 B

    const float PV = DIL ? -BIGF : BIGF;

    // stage the 5 source planes (PV outside the H x W interior)
    const float* gbase = u + (size_t)(b * C_ + c) * OHW_;
    for (int idx = threadIdx.x; idx < 5 * TP; idx += blockDim.x) {
        int pl = idx / TP;
        int rem = idx - pl * TP;
        int rr = rem / TW;
        int cc = rem - rr * TW;
        int gy = h0 - 3 + rr;
        int gx = w0 - 3 + cc;
        int oi = (o + pl + 6) & 7;     // (o + (pl-2)) mod 8
        float v = PV;
        if ((unsigned)gy < (unsigned)H_ && (unsigned)gx < (unsigned)W_)
            v = gbase[oi * HW_ + gy * W_ + gx];
        tile[idx] = v;
    }
    __syncthreads();

    int wI = threadIdx.x & 63;         // col within strip (lane)
    int rg = threadIdx.x >> 6;         // row-group == wave (0..3)
    int rbase = rg * RPT;
    int toff = rbase * TW + wI;
    float acc[RPT];
#pragma unroll
    for (int r = 0; r < RPT; r++) acc[r] = PV;

    const Geo6* gp = geo + o * KJ;
    const float* kp = kern + c * KJ;
    for (int j = 0; j < KJ; j++) {
        Geo6 g = gp[j];                // uniform -> s_load (scalar pipe, not DS)
        float kk = kp[j];              // uniform -> s_load
        float kks = DIL ? -kk : kk;
        float w00 = g.w00, w01 = g.w01, w10 = g.w10, w11 = g.w11;
        int a = g.off + toff;
        float c0[RPT + 1], c1[RPT + 1];
#pragma unroll
        for (int rr = 0; rr <= RPT; rr++) {
            af2 cc = *(const af2*)&tile[a + rr * TW];   // ds_read2_b32, perfect 2-way banks
            c0[rr] = cc.x;
            c1[rr] = cc.y;
        }
#pragma unroll
        for (int r = 0; r < RPT; r += 2) {
            float vx = fmaf(w00, c0[r],     kks);
            float vy = fmaf(w00, c0[r + 1], kks);
            vx = fmaf(w01, c1[r],     vx);
            vy = fmaf(w01, c1[r + 1], vy);
            vx = fmaf(w10, c0[r + 1], vx);
            vy = fmaf(w10, c0[r + 2], vy);
            vx = fmaf(w11, c1[r + 1], vx);
            vy = fmaf(w11, c1[r + 2], vy);
            if (DIL) {
                acc[r]     = fmaxf(acc[r],     vx);
                acc[r + 1] = fmaxf(acc[r + 1], vy);
            } else {
                acc[r]     = fminf(acc[r],     vx);
                acc[r + 1] = fminf(acc[r + 1], vy);
            }
        }
    }
    float* op = out + (size_t)bco * HW_ + (size_t)(h0 + rbase) * W_ + w0 + wI;
#pragma unroll
    for (int r = 0; r < RPT; r++) op[r * W_] = acc[r];
}

// ---------------- channel linear: z[b,d,o,h,w] = sum_c lin[d,c]*cat(d,e) ----------------
__global__ __launch_bounds__(256) void k_linear(const float* __restrict__ dbuf,
                                                const float* __restrict__ ebuf,
                                                const float* __restrict__ lin,
                                                float* __restrict__ out) {
    __shared__ float lsm[C_ * 2 * C_];
    for (int t = threadIdx.x; t < C_ * 2 * C_; t += blockDim.x) lsm[t] = lin[t];
    __syncthreads();
    int idx = blockIdx.x * blockDim.x + threadIdx.x;   // over B*O*H*W
    if (idx >= B_ * OHW_) return;
    int pos = idx % OHW_;
    int b = idx / OHW_;
    const float* dp = dbuf + (size_t)b * COHW_ + pos;
    const float* ep = ebuf + (size_t)b * COHW_ + pos;
    float vin[2 * C_];
    for (int c2 = 0; c2 < C_; c2++) {
        vin[c2] = dp[(size_t)c2 * OHW_];
        vin[C_ + c2] = ep[(size_t)c2 * OHW_];
    }
    for (int dch = 0; dch < C_; dch++) {
        float s = 0.f;
        for (int c2 = 0; c2 < 2 * C_; c2++) s += lsm[dch * 2 * C_ + c2] * vin[c2];
        out[(size_t)b * COHW_ + (size_t)dch * OHW_ + pos] = s;
    }
}

// ---------------- final: BN of input fused, max over O, project, sigmoid ----------------
__global__ __launch_bounds__(256) void k_final(const float* __restrict__ u,
                                               const float* __restrict__ fw,
                                               const float* __restrict__ sums,
                                               const float* __restrict__ gamma,
                                               const float* __restrict__ beta,
                                               float* __restrict__ out) {
    int idx = blockIdx.x * blockDim.x + threadIdx.x;   // B*H*W
    if (idx >= B_ * HW_) return;
    int pos = idx % HW_;
    int b = idx / HW_;
    const float* up = u + (size_t)b * COHW_ + pos;
    float y = 0.f;
    for (int c2 = 0; c2 < C_; c2++) {
        float m0 = sums[c2] * INVN_;
        float var = sums[C_ + c2] * INVN_ - m0 * m0;
        float alpha = rsqrtf(var + EPS_) * gamma[c2];
        float bshift = beta[c2] - m0 * alpha;
        float m = fmaf(alpha, up[(size_t)(c2 * O_) * HW_], bshift);
        for (int o2 = 1; o2 < O_; o2++)
            m = fmaxf(m, fmaf(alpha, up[(size_t)(c2 * O_ + o2) * HW_], bshift));
        y += fw[c2] * m;
    }
    out[idx] = 1.0f / (1.0f + expf(-y));
}

// ---------------- host orchestration ----------------
extern "C" void kernel_launch(void* const* d_in, const int* in_sizes, int n_in,
                              void* d_out, int out_size, void* d_ws, size_t ws_size,
                              hipStream_t stream) {
    const float* x          = (const float*)d_in[0];
    const float* lift_w     = (const float*)d_in[1];
    const float* lift_gamma = (const float*)d_in[2];
    const float* lift_beta  = (const float*)d_in[3];
    const float* pde_g      = (const float*)d_in[4];
    const float* pde_metric = (const float*)d_in[5];
    const float* pde_lin    = (const float*)d_in[6];
    const float* pde_gamma  = (const float*)d_in[7];
    const float* pde_beta   = (const float*)d_in[8];
    const float* final_w    = (const float*)d_in[9];
    float* out = (float*)d_out;

    // EXACT R9 footprint (proven): 3*NTOT + 25,348 table floats.
    // Geo6 table (8000 floats) ALIASES wr (18,816 floats) — wr is dead after k_lift_conv.
    float* ws   = (float*)d_ws;
    float* bufA = ws;                         // u (raw, pre-BN; readers apply affine)
    float* bufB = ws + (size_t)NTOT;          // scratch (convect out / z)
    float* bufC = ws + 2 * (size_t)NTOT;      // d
    float* wr   = ws + 3 * (size_t)NTOT;      // 18816 (lift weights, then Geo6 table)
    float* fyt  = wr + 18816;                 // 1000
    float* fxt  = fyt + 1000;                 // 1000
    float* c123 = fxt + 1000;                 // 375
    float* kern = c123 + 375;                 // 2000
    float* sums = kern + 2000;                // 32
    int* dy0t = (int*)(sums + 32);            // 1000
    int* dx0t = dy0t + 1000;                  // 1000
    int* dot_ = dx0t + 1000;                  // 125
    Geo6* geo = (Geo6*)wr;                    // 1000 records * 32 B = 8000 floats <= 18816

    const double ALPHA = 0.65;
    const double EXPO = 2.0 * ALPHA / (2.0 * ALPHA - 1.0);
    const double NU = (2.0 * ALPHA - 1.0) * pow(2.0 * ALPHA, -EXPO);
    const float nu_f = (float)NU;
    const float eh_f = (float)(EXPO / 2.0);

    dim3 rowGrid(H_, B_ * C_ * O_);
    dim3 convGrid(H_ / 2, B_ * C_ * O_);
    dim3 morphGrid((H_ / CR_T) * (W_ / CW_T), B_ * C_ * O_);   // 12 row strips x 3 col strips

    k_lift_weights<<<(C_ * O_ * 3 * 49 + 255) / 256, 256, 0, stream>>>(lift_w, wr);
    k_morph_geo<<<(KJ * O_ + 255) / 256, 256, 0, stream>>>(dy0t, dx0t, fyt, fxt, dot_, c123);
    k_lift_conv<<<rowGrid, 192, 0, stream>>>(x, wr, bufA);
    // wr is dead now; pack the static Geo6 table into its space
    k_geo_pack6<<<(O_ * KJ + 255) / 256, 256, 0, stream>>>(dy0t, dx0t, fyt, fxt, dot_, geo);

    hipMemsetAsync(sums, 0, 2 * C_ * sizeof(float), stream);
    k_bn_reduce<<<B_ * C_ * O_, 256, 0, stream>>>(bufA, sums);

    // gamma/beta of the BN that produced the current u (applied on read by convect/final)
    const float* cur_gamma = lift_gamma;
    const float* cur_beta  = lift_beta;

    for (int l = 0; l < NL_; l++) {
        const float* g0 = pde_g + (size_t)(l * 2 + 0) * C_ * 3;
        const float* g1 = pde_g + (size_t)(l * 2 + 1) * C_ * 3;
        const float* m0 = pde_metric + (size_t)(l * 2 + 0) * C_ * 3;
        const float* m1 = pde_metric + (size_t)(l * 2 + 1) * C_ * 3;
        const float* lin = pde_lin + (size_t)l * C_ * 2 * C_;

        // d = morph_dilate(convect(bn(u),g0))
        k_convect<<<convGrid, 192, 0, stream>>>(bufA, g0, sums, cur_gamma, cur_beta, bufB);
        k_morph_kern<<<(C_ * KJ + 255) / 256, 256, 0, stream>>>(m0, c123, kern, nu_f, eh_f);
        k_morph<1><<<morphGrid, 256, 0, stream>>>(bufB, geo, kern, bufC);
        // e = morph_erode(convect(bn(u),g1))  -- e overwrites u (dead after this convect)
        k_convect<<<convGrid, 192, 0, stream>>>(bufA, g1, sums, cur_gamma, cur_beta, bufB);
        k_morph_kern<<<(C_ * KJ + 255) / 256, 256, 0, stream>>>(m1, c123, kern, nu_f, eh_f);
        k_morph<0><<<morphGrid, 256, 0, stream>>>(bufB, geo, kern, bufA);
        // z = lin * cat(d,e) -> bufB ; stats(z) (apply deferred to readers)
        k_linear<<<(B_ * OHW_ + 255) / 256, 256, 0, stream>>>(bufC, bufA, lin, bufB);
        hipMemsetAsync(sums, 0, 2 * C_ * sizeof(float), stream);
        k_bn_reduce<<<B_ * C_ * O_, 256, 0, stream>>>(bufB, sums);
        cur_gamma = pde_gamma + l * C_;
        cur_beta  = pde_beta + l * C_;
        // rotate: new u = bufB (raw z)
        float* t = bufA; bufA = bufB; bufB = t;
    }

    k_final<<<(B_ * HW_ + 255) / 256, 256, 0, stream>>>(bufA, final_w, sums, cur_gamma, cur_beta, out);
}

// Round 17
// 4627.501 us; speedup vs baseline: 1.0547x; 1.0547x over previous
//
#include <hip/hip_runtime.h>
#include <math.h>

// ---------------- problem constants ----------------
constexpr int B_ = 4, C_ = 16, O_ = 8, H_ = 192, W_ = 192;
constexpr int KS_ = 7, NL_ = 4, KJ = 125;          // KJ = MS^3
constexpr int HW_  = H_ * W_;                      // 36864
constexpr int OHW_ = O_ * HW_;                     // 294912
constexpr int COHW_ = C_ * OHW_;                   // 4718592
constexpr int NTOT = B_ * COHW_;                   // 18874368 elements
constexpr float EPS_ = 1e-5f;
constexpr float BIGF = 1e30f;
constexpr int NPLANES = B_ * C_ * O_;              // 512
constexpr float INVN_ = 1.0f / (float)(B_ * O_ * HW_);

// morph tile geometry (R14 optimum): 64x8 output block, 256 threads = 4 waves, each wave
// one row-group with lanes == cols 0..63. Tile 5 x 14 x 70 = 19,600 B -> 8 blocks/CU x
// 4 waves = 32 waves/CU (100% of max). Wave-pure lanes make every stride-1 ds_read2 a
// perfect 2-way bank split with no stride padding (TW == CW+6). Measured: 528 us =
// ~99% of the ds_read2 throughput ceiling (28.3 GB @ ~54 TB/s effective) — the
// structural LDS-BW roofline for this 125-tap bilinear decomposition.
constexpr int CW_T = 64;               // output cols per block
constexpr int CR_T = 8;                // output rows per block
constexpr int TW_T = CW_T + 6;         // 70: tile row stride
constexpr int TR_T = CR_T + 6;         // 14: tile rows
constexpr int TP_T = TW_T * TR_T;      // 980: tile plane

typedef float af2 __attribute__((ext_vector_type(2), aligned(4)));  // ds_read2_b32

// static per-(o,j) morph geometry record (32 B, layer-independent) — lives in the dead
// lift-weight region of the workspace, so total footprint == the proven R9 layout.
struct alignas(32) Geo6 {
    int   off;                         // (dt+2)*TP + (dy0+3)*TW + (dx0+3)
    float w00, w01, w10, w11;
    int   pad0, pad1, pad2;
};

// ---------------- lift: rotated weights (double math == numpy) ----------------
__global__ void k_lift_weights(const float* __restrict__ w, float* __restrict__ wr) {
    int idx = blockIdx.x * blockDim.x + threadIdx.x;
    if (idx >= C_ * O_ * 3 * 49) return;
    int q = idx % 49;
    int i = (idx / 49) % 3;
    int o = (idx / (49 * 3)) % O_;
    int c = idx / (49 * 3 * O_);
    const double ctr = (KS_ - 1) / 2.0;
    int qy = q / KS_, qx = q % KS_;
    double ys = qy - ctr, xs = qx - ctr;
    double th = 2.0 * M_PI * (double)o / (double)O_;
    double sy = cos(th) * ys + sin(th) * xs + ctr;
    double sx = -sin(th) * ys + cos(th) * xs + ctr;
    double y0 = floor(sy), x0 = floor(sx);
    double fy = sy - y0, fx = sx - x0;
    double acc = 0.0;
    for (int dy = 0; dy < 2; dy++)
        for (int dx = 0; dx < 2; dx++) {
            int yi = (int)y0 + dy, xi = (int)x0 + dx;
            if (yi >= 0 && yi < KS_ && xi >= 0 && xi < KS_) {
                double wt = (dy ? fy : 1.0 - fy) * (dx ? fx : 1.0 - fx);
                acc += wt * (double)w[(c * 3 + i) * 49 + yi * KS_ + xi];
            }
        }
    wr[idx] = (float)acc;   // layout [c][o][i][q]
}

// ---------------- lift conv, reflect padding handled by index math ----------------
__global__ __launch_bounds__(192) void k_lift_conv(const float* __restrict__ x,
                                                   const float* __restrict__ wr,
                                                   float* __restrict__ u) {
    __shared__ float wsm[3 * 49];
    int h = blockIdx.x;
    int bco = blockIdx.y;               // b*C*O + c*O + o
    int o = bco % O_;
    int c = (bco / O_) % C_;
    int b = bco / (O_ * C_);
    const float* wp = wr + (size_t)(c * O_ + o) * 3 * 49;
    for (int t = threadIdx.x; t < 147; t += blockDim.x) wsm[t] = wp[t];
    __syncthreads();
    int wI = threadIdx.x;
    float acc = 0.f;
    for (int i = 0; i < 3; i++) {
        const float* xp = x + (size_t)(b * 3 + i) * HW_;
        for (int kh = 0; kh < 7; kh++) {
            int hy = h + kh - 3;
            hy = hy < 0 ? -hy : (hy >= H_ ? 2 * H_ - 2 - hy : hy);
            const float* xrow = xp + hy * W_;
            for (int kw = 0; kw < 7; kw++) {
                int wx = wI + kw - 3;
                wx = wx < 0 ? -wx : (wx >= W_ ? 2 * W_ - 2 - wx : wx);
                acc += wsm[i * 49 + kh * 7 + kw] * xrow[wx];
            }
        }
    }
    u[(size_t)bco * HW_ + h * W_ + wI] = acc;
}

// ---------------- batchnorm stats over (B,O,H,W) per channel (apply fused into readers) ------
__global__ __launch_bounds__(256) void k_bn_reduce(const float* __restrict__ u,
                                                   float* __restrict__ sums) {
    int c = (blockIdx.x / O_) % C_;
    const float* p = u + (size_t)blockIdx.x * HW_;
    float s = 0.f, s2 = 0.f;
    for (int t = threadIdx.x; t < HW_; t += blockDim.x) {
        float v = p[t];
        s += v; s2 += v * v;
    }
    for (int off = 32; off; off >>= 1) {
        s  += __shfl_down(s, off, 64);
        s2 += __shfl_down(s2, off, 64);
    }
    __shared__ float sh[8];
    int lane = threadIdx.x & 63, wid = threadIdx.x >> 6;
    if (lane == 0) { sh[wid] = s; sh[4 + wid] = s2; }
    __syncthreads();
    if (threadIdx.x == 0) {
        s = sh[0] + sh[1] + sh[2] + sh[3];
        s2 = sh[4] + sh[5] + sh[6] + sh[7];
        atomicAdd(&sums[c], s);
        atomicAdd(&sums[C_ + c], s2);
    }
}

// ---------------- convect: 8-tap trilinear gather, BN fused on read, 2 rows/thread ------------
__global__ __launch_bounds__(192) void k_convect(const float* __restrict__ u,
                                                 const float* __restrict__ g,
                                                 const float* __restrict__ sums,
                                                 const float* __restrict__ gamma,
                                                 const float* __restrict__ beta,
                                                 float* __restrict__ out) {
    int h0 = blockIdx.x * 2;
    int bco = blockIdx.y;
    int o = bco % O_;
    int c = (bco / O_) % C_;
    int b = bco / (O_ * C_);
    float m = sums[c] * INVN_;
    float var = sums[C_ + c] * INVN_ - m * m;
    float alpha = rsqrtf(var + EPS_) * gamma[c];
    float bshift = beta[c] - m * alpha;
    float gx = g[c * 3 + 0], gy = g[c * 3 + 1], gth = g[c * 3 + 2];
    float th = ((float)(2.0 * M_PI) * (float)o) / (float)O_;
    float ct = cosf(th), st = sinf(th);
    float sx = ct * gx - st * gy;
    float sy = st * gx + ct * gy;
    float so = gth / (float)(2.0 * M_PI / (double)O_);
    float o_src = (float)o - so;
    float o0f = floorf(o_src); float fo = o_src - o0f;
    int o0 = (int)o0f;
    float ny = -sy; float y0f = floorf(ny); float fy = ny - y0f; int y0 = (int)y0f;
    float nx = -sx; float x0f = floorf(nx); float fx = nx - x0f; int x0 = (int)x0f;
    int oiA = ((o0 % O_) + O_) % O_;
    int oiB = (oiA + 1) % O_;
    const float* base = u + (size_t)(b * C_ + c) * OHW_;
    int wI = threadIdx.x;
#pragma unroll
    for (int r = 0; r < 2; r++) {
        int h = h0 + r;
        float acc = 0.f;
        for (int dd = 0; dd < 2; dd++) {
            float wo = dd ? fo : 1.0f - fo;
            const float* up = base + (size_t)(dd ? oiB : oiA) * HW_;
            for (int dy = 0; dy < 2; dy++) {
                int yy = h + y0 + dy;
                yy = min(max(yy, 0), H_ - 1);
                float wy = dy ? fy : 1.0f - fy;
                const float* row = up + yy * W_;
                for (int dx = 0; dx < 2; dx++) {
                    int xx = wI + x0 + dx;
                    xx = min(max(xx, 0), W_ - 1);
                    float wgt = wo * wy * (dx ? fx : 1.0f - fx);
                    acc += wgt * row[xx];
                }
            }
        }
        out[(size_t)bco * HW_ + h * W_ + wI] = fmaf(alpha, acc, bshift);
    }
}

// ---------------- morph static geometry (double math == numpy) ----------------
__global__ void k_morph_geo(int* __restrict__ dy0t, int* __restrict__ dx0t,
                            float* __restrict__ fyt, float* __restrict__ fxt,
                            int* __restrict__ dot_, float* __restrict__ c123) {
    int idx = blockIdx.x * blockDim.x + threadIdx.x;
    if (idx >= KJ * O_) return;
    int j = idx / O_, o = idx % O_;
    int dt = j / 25 - 2;
    int dy = (j / 5) % 5 - 2;
    int dx = j % 5 - 2;
    double dth = 2.0 * M_PI / (double)O_;
    double th = (double)o * dth;
    double gx = cos(th) * (double)dx - sin(th) * (double)dy;
    double gy = sin(th) * (double)dx + cos(th) * (double)dy;
    dx0t[j * O_ + o] = (int)floor(gx);
    fxt[j * O_ + o] = (float)(gx - floor(gx));
    dy0t[j * O_ + o] = (int)floor(gy);
    fyt[j * O_ + o] = (float)(gy - floor(gy));
    if (o == 0) {
        dot_[j] = dt;
        double a = (double)dt * dth;
        c123[j * 3 + 0] = (float)(cos(a / 2) * dx + sin(a / 2) * dy);
        c123[j * 3 + 1] = (float)(-sin(a / 2) * dx + cos(a / 2) * dy);
        c123[j * 3 + 2] = (float)a;
    }
}

__global__ void k_morph_kern(const float* __restrict__ wm, const float* __restrict__ c123,
                             float* __restrict__ kern, float nu_f, float eh_f) {
    int idx = blockIdx.x * blockDim.x + threadIdx.x;
    if (idx >= C_ * KJ) return;
    int c = idx / KJ, j = idx % KJ;
    float C1 = c123[j * 3 + 0], C2 = c123[j * 3 + 1], C3 = c123[j * 3 + 2];
    float rho2 = wm[c * 3 + 0] * C1 * C1 + wm[c * 3 + 1] * C2 * C2 + wm[c * 3 + 2] * C3 * C3;
    kern[c * KJ + j] = nu_f * powf(rho2, eh_f);
}

// ---------------- pack static per-(o,j) geometry (once per launch, into dead wr region) ------
__global__ void k_geo_pack6(const int* __restrict__ dy0t, const int* __restrict__ dx0t,
                            const float* __restrict__ fyt, const float* __restrict__ fxt,
                            const int* __restrict__ dot_, Geo6* __restrict__ geo) {
    int idx = blockIdx.x * blockDim.x + threadIdx.x;
    if (idx >= O_ * KJ) return;
    int j = idx % KJ;
    int o = idx / KJ;
    float fy = fyt[j * O_ + o];
    float fx = fxt[j * O_ + o];
    float wy0 = 1.0f - fy, wx0 = 1.0f - fx;
    Geo6 g;
    g.off = (dot_[j] + 2) * TP_T + (dy0t[j * O_ + o] + 3) * TW_T + (dx0t[j * O_ + o] + 3);
    g.w00 = wy0 * wx0;
    g.w01 = wy0 * fx;
    g.w10 = fy * wx0;
    g.w11 = fy * fx;
    g.pad0 = 0; g.pad1 = 0; g.pad2 = 0;
    geo[o * KJ + j] = g;
}

// ---------------- morph main: 64x8 tile, 256 threads, wave-per-row-group, 32 waves/CU --------
template <int DIL>
__global__ __launch_bounds__(256) void k_morph(const float* __restrict__ u,
                                               const Geo6* __restrict__ geo,
                                               const float* __restrict__ kern,
                                               float* __restrict__ out) {
    constexpr int CW = CW_T, CR = CR_T, TW = TW_T, TP = TP_T;
    constexpr int RPT = 2;             // rows per thread
    int cx = blockIdx.x % 3;           // col strip (W/64 = 3)
    int hs = blockIdx.x / 3;           // row strip (H/8 = 24)
    int h0 = hs * CR;
    int w0 = cx * CW;
    int bco = blockIdx.y;
    int o = bco % O_;
    int c = (bco / O_) % C_;
    int b = bco / (O_ * C_);

    __shared__ float tile[5 * TP];     // 19600 B

    const float PV = DIL ? -BIGF : BIGF;

    // stage the 5 source planes (PV outside the H x W interior)
    const float* gbase = u + (size_t)(b * C_ + c) * OHW_;
    for (int idx = threadIdx.x; idx < 5 * TP; idx += blockDim.x) {
        int pl = idx / TP;
        int rem = idx - pl * TP;
        int rr = rem / TW;
        int cc = rem - rr * TW;
        int gy = h0 - 3 + rr;
        int gx = w0 - 3 + cc;
        int oi = (o + pl + 6) & 7;     // (o + (pl-2)) mod 8
        float v = PV;
        if ((unsigned)gy < (unsigned)H_ && (unsigned)gx < (unsigned)W_)
            v = gbase[oi * HW_ + gy * W_ + gx];
        tile[idx] = v;
    }
    __syncthreads();

    int wI = threadIdx.x & 63;         // col within strip (lane)
    int rg = threadIdx.x >> 6;         // row-group == wave (0..3)
    int rbase = rg * RPT;
    int toff = rbase * TW + wI;
    float acc[RPT];
#pragma unroll
    for (int r = 0; r < RPT; r++) acc[r] = PV;

    const Geo6* gp = geo + o * KJ;
    const float* kp = kern + c * KJ;
    for (int j = 0; j < KJ; j++) {
        Geo6 g = gp[j];                // uniform -> s_load (scalar pipe, not DS)
        float kk = kp[j];              // uniform -> s_load
        float kks = DIL ? -kk : kk;
        float w00 = g.w00, w01 = g.w01, w10 = g.w10, w11 = g.w11;
        int a = g.off + toff;
        float c0[RPT + 1], c1[RPT + 1];
#pragma unroll
        for (int rr = 0; rr <= RPT; rr++) {
            af2 cc = *(const af2*)&tile[a + rr * TW];   // ds_read2_b32, perfect 2-way banks
            c0[rr] = cc.x;
            c1[rr] = cc.y;
        }
#pragma unroll
        for (int r = 0; r < RPT; r += 2) {
            float vx = fmaf(w00, c0[r],     kks);
            float vy = fmaf(w00, c0[r + 1], kks);
            vx = fmaf(w01, c1[r],     vx);
            vy = fmaf(w01, c1[r + 1], vy);
            vx = fmaf(w10, c0[r + 1], vx);
            vy = fmaf(w10, c0[r + 2], vy);
            vx = fmaf(w11, c1[r + 1], vx);
            vy = fmaf(w11, c1[r + 2], vy);
            if (DIL) {
                acc[r]     = fmaxf(acc[r],     vx);
                acc[r + 1] = fmaxf(acc[r + 1], vy);
            } else {
                acc[r]     = fminf(acc[r],     vx);
                acc[r + 1] = fminf(acc[r + 1], vy);
            }
        }
    }
    float* op = out + (size_t)bco * HW_ + (size_t)(h0 + rbase) * W_ + w0 + wI;
#pragma unroll
    for (int r = 0; r < RPT; r++) op[r * W_] = acc[r];
}

// ---------------- channel linear: z[b,d,o,h,w] = sum_c lin[d,c]*cat(d,e) ----------------
__global__ __launch_bounds__(256) void k_linear(const float* __restrict__ dbuf,
                                                const float* __restrict__ ebuf,
                                                const float* __restrict__ lin,
                                                float* __restrict__ out) {
    __shared__ float lsm[C_ * 2 * C_];
    for (int t = threadIdx.x; t < C_ * 2 * C_; t += blockDim.x) lsm[t] = lin[t];
    __syncthreads();
    int idx = blockIdx.x * blockDim.x + threadIdx.x;   // over B*O*H*W
    if (idx >= B_ * OHW_) return;
    int pos = idx % OHW_;
    int b = idx / OHW_;
    const float* dp = dbuf + (size_t)b * COHW_ + pos;
    const float* ep = ebuf + (size_t)b * COHW_ + pos;
    float vin[2 * C_];
    for (int c2 = 0; c2 < C_; c2++) {
        vin[c2] = dp[(size_t)c2 * OHW_];
        vin[C_ + c2] = ep[(size_t)c2 * OHW_];
    }
    for (int dch = 0; dch < C_; dch++) {
        float s = 0.f;
        for (int c2 = 0; c2 < 2 * C_; c2++) s += lsm[dch * 2 * C_ + c2] * vin[c2];
        out[(size_t)b * COHW_ + (size_t)dch * OHW_ + pos] = s;
    }
}

// ---------------- final: BN of input fused, max over O, project, sigmoid ----------------
__global__ __launch_bounds__(256) void k_final(const float* __restrict__ u,
                                               const float* __restrict__ fw,
                                               const float* __restrict__ sums,
                                               const float* __restrict__ gamma,
                                               const float* __restrict__ beta,
                                               float* __restrict__ out) {
    int idx = blockIdx.x * blockDim.x + threadIdx.x;   // B*H*W
    if (idx >= B_ * HW_) return;
    int pos = idx % HW_;
    int b = idx / HW_;
    const float* up = u + (size_t)b * COHW_ + pos;
    float y = 0.f;
    for (int c2 = 0; c2 < C_; c2++) {
        float m0 = sums[c2] * INVN_;
        float var = sums[C_ + c2] * INVN_ - m0 * m0;
        float alpha = rsqrtf(var + EPS_) * gamma[c2];
        float bshift = beta[c2] - m0 * alpha;
        float m = fmaf(alpha, up[(size_t)(c2 * O_) * HW_], bshift);
        for (int o2 = 1; o2 < O_; o2++)
            m = fmaxf(m, fmaf(alpha, up[(size_t)(c2 * O_ + o2) * HW_], bshift));
        y += fw[c2] * m;
    }
    out[idx] = 1.0f / (1.0f + expf(-y));
}

// ---------------- host orchestration ----------------
extern "C" void kernel_launch(void* const* d_in, const int* in_sizes, int n_in,
                              void* d_out, int out_size, void* d_ws, size_t ws_size,
                              hipStream_t stream) {
    const float* x          = (const float*)d_in[0];
    const float* lift_w     = (const float*)d_in[1];
    const float* lift_gamma = (const float*)d_in[2];
    const float* lift_beta  = (const float*)d_in[3];
    const float* pde_g      = (const float*)d_in[4];
    const float* pde_metric = (const float*)d_in[5];
    const float* pde_lin    = (const float*)d_in[6];
    const float* pde_gamma  = (const float*)d_in[7];
    const float* pde_beta   = (const float*)d_in[8];
    const float* final_w    = (const float*)d_in[9];
    float* out = (float*)d_out;

    // EXACT R9 footprint (proven): 3*NTOT + 25,348 table floats.
    // Geo6 table (8000 floats) ALIASES wr (18,816 floats) — wr is dead after k_lift_conv.
    float* ws   = (float*)d_ws;
    float* bufA = ws;                         // u (raw, pre-BN; readers apply affine)
    float* bufB = ws + (size_t)NTOT;          // scratch (convect out / z)
    float* bufC = ws + 2 * (size_t)NTOT;      // d
    float* wr   = ws + 3 * (size_t)NTOT;      // 18816 (lift weights, then Geo6 table)
    float* fyt  = wr + 18816;                 // 1000
    float* fxt  = fyt + 1000;                 // 1000
    float* c123 = fxt + 1000;                 // 375
    float* kern = c123 + 375;                 // 2000
    float* sums = kern + 2000;                // 32
    int* dy0t = (int*)(sums + 32);            // 1000
    int* dx0t = dy0t + 1000;                  // 1000
    int* dot_ = dx0t + 1000;                  // 125
    Geo6* geo = (Geo6*)wr;                    // 1000 records * 32 B = 8000 floats <= 18816

    const double ALPHA = 0.65;
    const double EXPO = 2.0 * ALPHA / (2.0 * ALPHA - 1.0);
    const double NU = (2.0 * ALPHA - 1.0) * pow(2.0 * ALPHA, -EXPO);
    const float nu_f = (float)NU;
    const float eh_f = (float)(EXPO / 2.0);

    dim3 rowGrid(H_, B_ * C_ * O_);
    dim3 convGrid(H_ / 2, B_ * C_ * O_);
    dim3 morphGrid((H_ / CR_T) * (W_ / CW_T), B_ * C_ * O_);   // 24 row strips x 3 col strips

    k_lift_weights<<<(C_ * O_ * 3 * 49 + 255) / 256, 256, 0, stream>>>(lift_w, wr);
    k_morph_geo<<<(KJ * O_ + 255) / 256, 256, 0, stream>>>(dy0t, dx0t, fyt, fxt, dot_, c123);
    k_lift_conv<<<rowGrid, 192, 0, stream>>>(x, wr, bufA);
    // wr is dead now; pack the static Geo6 table into its space
    k_geo_pack6<<<(O_ * KJ + 255) / 256, 256, 0, stream>>>(dy0t, dx0t, fyt, fxt, dot_, geo);

    hipMemsetAsync(sums, 0, 2 * C_ * sizeof(float), stream);
    k_bn_reduce<<<B_ * C_ * O_, 256, 0, stream>>>(bufA, sums);

    // gamma/beta of the BN that produced the current u (applied on read by convect/final)
    const float* cur_gamma = lift_gamma;
    const float* cur_beta  = lift_beta;

    for (int l = 0; l < NL_; l++) {
        const float* g0 = pde_g + (size_t)(l * 2 + 0) * C_ * 3;
        const float* g1 = pde_g + (size_t)(l * 2 + 1) * C_ * 3;
        const float* m0 = pde_metric + (size_t)(l * 2 + 0) * C_ * 3;
        const float* m1 = pde_metric + (size_t)(l * 2 + 1) * C_ * 3;
        const float* lin = pde_lin + (size_t)l * C_ * 2 * C_;

        // d = morph_dilate(convect(bn(u),g0))
        k_convect<<<convGrid, 192, 0, stream>>>(bufA, g0, sums, cur_gamma, cur_beta, bufB);
        k_morph_kern<<<(C_ * KJ + 255) / 256, 256, 0, stream>>>(m0, c123, kern, nu_f, eh_f);
        k_morph<1><<<morphGrid, 256, 0, stream>>>(bufB, geo, kern, bufC);
        // e = morph_erode(convect(bn(u),g1))  -- e overwrites u (dead after this convect)
        k_convect<<<convGrid, 192, 0, stream>>>(bufA, g1, sums, cur_gamma, cur_beta, bufB);
        k_morph_kern<<<(C_ * KJ + 255) / 256, 256, 0, stream>>>(m1, c123, kern, nu_f, eh_f);
        k_morph<0><<<morphGrid, 256, 0, stream>>>(bufB, geo, kern, bufA);
        // z = lin * cat(d,e) -> bufB ; stats(z) (apply deferred to readers)
        k_linear<<<(B_ * OHW_ + 255) / 256, 256, 0, stream>>>(bufC, bufA, lin, bufB);
        hipMemsetAsync(sums, 0, 2 * C_ * sizeof(float), stream);
        k_bn_reduce<<<B_ * C_ * O_, 256, 0, stream>>>(bufB, sums);
        cur_gamma = pde_gamma + l * C_;
        cur_beta  = pde_beta + l * C_;
        // rotate: new u = bufB (raw z)
        float* t = bufA; bufA = bufB; bufB = t;
    }

    k_final<<<(B_ * HW_ + 255) / 256, 256, 0, stream>>>(bufA, final_w, sums, cur_gamma, cur_beta, out);
}